// Round 15
// baseline (191.841 us; speedup 1.0000x reference)
//
#include <hip/hip_runtime.h>
#include <cstdint>
#include <cmath>

#define B_ 2
#define C_ 64
#define H_ 128
#define W_ 240
#define HW_ (H_*W_)
#define OFF_CH 144
#define MASK_CH 72
#define ALIGNED_SZ (B_*C_*HW_)   /* 3932160 floats */

typedef __bf16 bf16x8 __attribute__((ext_vector_type(8)));
typedef float f32x4 __attribute__((ext_vector_type(4)));
typedef short short4v __attribute__((ext_vector_type(4)));
typedef unsigned short ushort_t;

__device__ __forceinline__ ushort_t f2bf(float f) {
    unsigned u = __float_as_uint(f);
    u += 0x7fffu + ((u >> 16) & 1u);          // round-to-nearest-even
    return (ushort_t)(u >> 16);
}
__device__ __forceinline__ float bf2f(ushort_t b) {
    return __uint_as_float((unsigned)b << 16);
}
__device__ __forceinline__ float bf_lo(int q) {
    return __uint_as_float((unsigned)q << 16);
}
__device__ __forceinline__ float bf_hi(int q) {
    return __uint_as_float((unsigned)q & 0xffff0000u);
}

// workspace layout (byte offsets); total 32,956,416 B
// pin: nbr half = 8 per-dg planes [dg][HW][8ch]; ref half = [HW][64].
// HBUF region is DEAD after conv2 -> reused as dconv khalf-1 bf16 partial.
#define W1P_OFF  0u
#define W2P_OFF  147456u
#define PIN_OFF  442368u      /* [B][2][HW][64] bf16 = 15,728,640 */
#define HBUF_OFF 16171008u    /* [B][H][W][64]  bf16 =  7,864,320 */
#define MASK_OFF 24035328u    /* [B][72][H][W]  bf16 =  8,847,360 */
#define WDP_OFF  32882688u    /* [18][4][64][8] bf16 =     73,728 */

// ---------------------------------------------------------------------------
// Repack all weights into MFMA A-fragment layouts (unchanged, proven).
// ---------------------------------------------------------------------------
__global__ __launch_bounds__(256) void pack_weights(
    const float* __restrict__ w1, const float* __restrict__ w2,
    const float* __restrict__ wd,
    ushort_t* __restrict__ w1pf, ushort_t* __restrict__ w2pf,
    ushort_t* __restrict__ wdp)
{
    int t = blockIdx.x * 256 + threadIdx.x;
    if (t < 73728) {
        int j = t & 7, lane = (t >> 3) & 63, r = t >> 9;
        int wv = r & 3, ct = r >> 2;
        int tap = ct % 9, chunk = ct / 9;
        int oc = wv * 16 + (lane & 15);
        int ci = chunk * 32 + ((lane >> 4) << 3) + j;
        w1pf[t] = f2bf(w1[((size_t)oc * 128 + ci) * 9 + tap]);
    } else if (t < 73728 + 147456) {
        int f = t - 73728;
        int j = f & 7, lane = (f >> 3) & 63, r = f >> 9;
        int wv = r & 3, q = r >> 2;
        int tap = q % 9, oc2 = q / 9;
        int chunk = oc2 & 1, ocg = oc2 >> 1;
        int oc = ocg * 64 + wv * 16 + (lane & 15);
        int ci = chunk * 32 + ((lane >> 4) << 3) + j;
        float v = (oc < 216) ? w2[((size_t)oc * 64 + ci) * 9 + tap] : 0.f;
        w2pf[f] = f2bf(v);
    } else if (t < 73728 + 147456 + 36864) {
        int f = t - 221184;
        int j = f & 7, lane = (f >> 3) & 63, sg = f >> 9;
        int g = sg & 3, s = sg >> 2;
        int oc = g * 16 + (lane & 15);
        int K = s * 32 + ((lane >> 4) << 3) + j;
        int dg = K / 72, rr = K - dg * 72;
        int tap = rr >> 3, ci = (dg << 3) + (rr & 7);
        wdp[f] = f2bf(wd[((size_t)oc * 64 + ci) * 9 + tap]);
    }
}

// ---------------------------------------------------------------------------
// Repack input. nbr -> per-dg planes [b][dg][HW][8]; ref -> [b][HW][64].
// ---------------------------------------------------------------------------
__global__ __launch_bounds__(256) void pack_input(
    const float* __restrict__ nbr, const float* __restrict__ ref,
    ushort_t* __restrict__ pin)
{
    int f = blockIdx.x * 256 + threadIdx.x;    // < 983040 = B*HW*16
    int civec = f & 15;
    int rem = f >> 4;                          // b*HW + pix
    int b = rem / HW_, pix = rem - b * HW_;
    const int half = civec >> 3;
    const float* src = (half == 0) ? (nbr + (size_t)b * 64 * HW_)
                                   : (ref + (size_t)b * 64 * HW_);
    int cbase = (civec & 7) * 8;
    union { ushort_t u[8]; int4 v; } o;
#pragma unroll
    for (int j = 0; j < 8; ++j)
        o.u[j] = f2bf(src[(size_t)(cbase + j) * HW_ + pix]);
    size_t dst;
    if (half == 0) {    // dg-plane layout: dg = civec&7
        dst = (size_t)b * 2 * HW_ * 64 + (size_t)(civec & 7) * HW_ * 8 + (size_t)pix * 8;
    } else {            // ref half: [HW][64]
        dst = ((size_t)(b * 2 + 1) * HW_ + pix) * 64 + cbase;
    }
    *(int4*)&pin[dst] = o.v;
}

// ---------------------------------------------------------------------------
// conv1 via MFMA implicit GEMM (round-11 proven version, 1 row/block).
// ---------------------------------------------------------------------------
__global__ __launch_bounds__(256) void conv1_mfma(
    const ushort_t* __restrict__ pin, const float* __restrict__ b1,
    const ushort_t* __restrict__ w1pf, ushort_t* __restrict__ hbuf)
{
    const int bx = blockIdx.x, y = blockIdx.y, b = blockIdx.z;
    const int x0 = bx * 48;
    const int tid = threadIdx.x;
    const int wv = tid >> 6, lane = tid & 63;
    const int l15 = lane & 15, k8 = (lane >> 4) << 3;

    __shared__ __align__(16) ushort_t s_in[3 * 50 * 40];

    f32x4 acc[3];
#pragma unroll
    for (int i = 0; i < 3; ++i) acc[i] = (f32x4){0.f, 0.f, 0.f, 0.f};

    for (int chunk = 0; chunk < 4; ++chunk) {
        const int ci0 = chunk << 5;
        for (int i = tid; i < 600; i += 256) {
            int cvec = i & 3, rc = i >> 2;
            int row = rc / 50, col = rc - row * 50;
            int gy = y + row - 1, gx = x0 + col - 1;
            int ci = ci0 + cvec * 8;
            int half = ci >> 6, cw = ci & 63;
            int4 v = {0, 0, 0, 0};
            if ((unsigned)gy < (unsigned)H_ && (unsigned)gx < (unsigned)W_) {
                size_t srca;
                if (half == 0)
                    srca = (size_t)b * 2 * HW_ * 64 + (size_t)(cw >> 3) * HW_ * 8
                         + (size_t)(gy * W_ + gx) * 8;
                else
                    srca = ((size_t)(b * 2 + 1) * HW_ + (size_t)gy * W_ + gx) * 64 + cw;
                v = *(const int4*)&pin[srca];
            }
            *(int4*)&s_in[(row * 50 + col) * 40 + cvec * 8] = v;
        }
        bf16x8 af[9];
#pragma unroll
        for (int tap = 0; tap < 9; ++tap)
            af[tap] = *(const bf16x8*)&w1pf[((((size_t)chunk * 9 + tap) * 4 + wv) * 64 + lane) * 8];
        __syncthreads();

#pragma unroll
        for (int tap = 0; tap < 9; ++tap) {
            const int ky = tap / 3, kx = tap - ky * 3;
#pragma unroll
            for (int pt = 0; pt < 3; ++pt) {
                int col = (pt << 4) + l15 + kx;
                bf16x8 bb = *(const bf16x8*)&s_in[(ky * 50 + col) * 40 + k8];
                acc[pt] = __builtin_amdgcn_mfma_f32_16x16x32_bf16(af[tap], bb, acc[pt], 0, 0, 0);
            }
        }
        __syncthreads();
    }

    const int ocb = (wv << 4) + ((lane >> 4) << 2);
    float bias[4];
#pragma unroll
    for (int r = 0; r < 4; ++r) bias[r] = b1[ocb + r];
#pragma unroll
    for (int pt = 0; pt < 3; ++pt) {
        int gx = x0 + (pt << 4) + l15;
        union { ushort_t u[4]; short4v s; } o;
#pragma unroll
        for (int r = 0; r < 4; ++r) {
            float v = acc[pt][r] + bias[r];
            v = (v >= 0.f) ? v : 0.1f * v;
            o.u[r] = f2bf(v);
        }
        *(short4v*)&hbuf[(((size_t)b * H_ + y) * W_ + gx) * 64 + ocb] = o.s;
    }
}

// ---------------------------------------------------------------------------
// conv2 (round-11 proven version: 1 row, 1 oc-group per block).
// grid (5, 128, 8), z = b*4 + ocg.  Best of the 1/2/4-ocg family.
// ---------------------------------------------------------------------------
__global__ __launch_bounds__(256) void conv2_mfma(
    const ushort_t* __restrict__ hbuf, const float* __restrict__ b2,
    const ushort_t* __restrict__ w2pf,
    float* __restrict__ off_out, ushort_t* __restrict__ maskbuf)
{
    const int bx = blockIdx.x, y = blockIdx.y;
    const int b = blockIdx.z >> 2, ocg = blockIdx.z & 3;
    const int x0 = bx * 48;
    const int tid = threadIdx.x;
    const int wv = tid >> 6, lane = tid & 63;
    const int l15 = lane & 15, k8 = (lane >> 4) << 3;

    __shared__ __align__(16) ushort_t s_in[3 * 50 * 40];

    f32x4 acc[3];
#pragma unroll
    for (int i = 0; i < 3; ++i) acc[i] = (f32x4){0.f, 0.f, 0.f, 0.f};

    for (int chunk = 0; chunk < 2; ++chunk) {
        const int ci0 = chunk << 5;
        for (int i = tid; i < 600; i += 256) {
            int cvec = i & 3, rc = i >> 2;
            int row = rc / 50, col = rc - row * 50;
            int gy = y + row - 1, gx = x0 + col - 1;
            int4 v = {0, 0, 0, 0};
            if ((unsigned)gy < (unsigned)H_ && (unsigned)gx < (unsigned)W_)
                v = *(const int4*)&hbuf[(((size_t)b * H_ + gy) * W_ + gx) * 64 + ci0 + cvec * 8];
            *(int4*)&s_in[(row * 50 + col) * 40 + cvec * 8] = v;
        }
        bf16x8 af[9];
#pragma unroll
        for (int tap = 0; tap < 9; ++tap)
            af[tap] = *(const bf16x8*)&w2pf[(((((size_t)ocg * 2 + chunk) * 9 + tap) * 4 + wv) * 64 + lane) * 8];
        __syncthreads();

#pragma unroll
        for (int tap = 0; tap < 9; ++tap) {
            const int ky = tap / 3, kx = tap - ky * 3;
#pragma unroll
            for (int pt = 0; pt < 3; ++pt) {
                int col = (pt << 4) + l15 + kx;
                bf16x8 bb = *(const bf16x8*)&s_in[(ky * 50 + col) * 40 + k8];
                acc[pt] = __builtin_amdgcn_mfma_f32_16x16x32_bf16(af[tap], bb, acc[pt], 0, 0, 0);
            }
        }
        __syncthreads();
    }

    const int ocb = (wv << 4) + ((lane >> 4) << 2);
#pragma unroll
    for (int pt = 0; pt < 3; ++pt) {
        int gx = x0 + (pt << 4) + l15;
#pragma unroll
        for (int r = 0; r < 4; ++r) {
            int co = (ocg << 6) + ocb + r;
            if (co < 216) {
                float v = acc[pt][r] + b2[co];
                if (co < 144) {
                    off_out[((size_t)b * OFF_CH + co) * HW_ + y * W_ + gx] = v;
                } else {
                    maskbuf[((size_t)b * MASK_CH + (co - 144)) * HW_ + y * W_ + gx] =
                        f2bf(1.f / (1.f + expf(-v)));
                }
            }
        }
    }
}

// ---------------------------------------------------------------------------
// dconv v9 (round-12 proven): barrier-free ping-pong + split-K x2.
// launch_bounds min-waves raised 4->8 (VGPR=44 fits) to loosen any
// declared-occupancy cap.
// ---------------------------------------------------------------------------
struct OffRec { float dy, dx, m; };
struct Stage  { int4 g0, g1, g2, g3; float w0, w1, w2, w3; };

__global__ __launch_bounds__(256, 8) void dconv_mfma(
    const ushort_t* __restrict__ pin,
    const float* __restrict__ offs,
    const ushort_t* __restrict__ maskbuf,
    const ushort_t* __restrict__ wdp, const float* __restrict__ bd,
    float* __restrict__ outp, ushort_t* __restrict__ partial)
{
    const int bid = blockIdx.x;
    const int kh  = (bid >= 960) ? 1 : 0;
    const int sb  = bid - kh * 960;
    const int nid = (sb & 7) * 120 + (sb >> 3);
    const int b   = nid / 480;
    const int rr_ = nid - b * 480;
    const int byt = rr_ / 15, bxt = rr_ - byt * 15;   // byt 0..31
    const int x0 = bxt << 4, y0 = byt << 2;
    const int base = kh * 9;                          // slice base

    const int tid = threadIdx.x;
    const int wv = tid >> 6, lane = tid & 63;
    const int l15 = lane & 15, hi4 = lane >> 4;       // hi4 = k-group

    const int x = x0 + l15, y = y0 + wv;              // this lane's pixel
    const size_t pix = (size_t)y * W_ + x;
    const size_t pinb = (size_t)b * 2 * HW_ * 64;     // nbr dg-planes base
    const float* offp = offs + (size_t)b * OFF_CH * HW_ + pix;
    const ushort_t* mkp = maskbuf + (size_t)b * MASK_CH * HW_ + pix;

    f32x4 acc0 = {0.f,0.f,0.f,0.f}, acc1 = {0.f,0.f,0.f,0.f};
    f32x4 acc2 = {0.f,0.f,0.f,0.f}, acc3 = {0.f,0.f,0.f,0.f};

    auto load_off = [&](int s) -> OffRec {
        int K = (s << 5) + (hi4 << 3);
        int dg = K / 72, r2 = K - dg * 72, tap = r2 >> 3;
        OffRec o;
        o.dy = offp[(size_t)(dg * 18 + tap) * HW_];
        o.dx = offp[(size_t)(dg * 18 + 9 + tap) * HW_];
        o.m  = bf2f(mkp[(size_t)(dg * 9 + tap) * HW_]);
        return o;
    };
    auto sample = [&](int s, OffRec of) -> Stage {
        int K = (s << 5) + (hi4 << 3);
        int dg = K / 72, rm = K - dg * 72, tap = rm >> 3;
        int ky = tap / 3 - 1, kx = tap % 3 - 1;
        float py  = (float)(y + ky) + of.dy;
        float pxf = (float)(x + kx) + of.dx;
        float yf = floorf(py), xf = floorf(pxf);
        float wy = py - yf, wx = pxf - xf;
        int yi = (int)yf, xi = (int)xf;
        bool y0v = (unsigned)yi < (unsigned)H_;
        bool y1v = (unsigned)(yi + 1) < (unsigned)H_;
        bool x0v = (unsigned)xi < (unsigned)W_;
        bool x1v = (unsigned)(xi + 1) < (unsigned)W_;
        Stage st;
        st.w0 = (y0v && x0v) ? (1.f - wy) * (1.f - wx) * of.m : 0.f;
        st.w1 = (y0v && x1v) ? (1.f - wy) * wx         * of.m : 0.f;
        st.w2 = (y1v && x0v) ? wy         * (1.f - wx) * of.m : 0.f;
        st.w3 = (y1v && x1v) ? wy         * wx         * of.m : 0.f;
        int yc0 = min(max(yi, 0), H_ - 1), yc1 = min(max(yi + 1, 0), H_ - 1);
        int xc0 = min(max(xi, 0), W_ - 1), xc1 = min(max(xi + 1, 0), W_ - 1);
        const size_t dgb = pinb + (size_t)dg * HW_ * 8;   // 16B px records
        st.g0 = *(const int4*)&pin[dgb + (size_t)(yc0 * W_ + xc0) * 8];
        st.g1 = *(const int4*)&pin[dgb + (size_t)(yc0 * W_ + xc1) * 8];
        st.g2 = *(const int4*)&pin[dgb + (size_t)(yc1 * W_ + xc0) * 8];
        st.g3 = *(const int4*)&pin[dgb + (size_t)(yc1 * W_ + xc1) * 8];
        return st;
    };

    // ---- prologue: stages for local slices 0,1; offsets for 2,3 ----
    Stage  P0 = sample(base + 0, load_off(base + 0));
    Stage  P1 = sample(base + 1, load_off(base + 1));
    OffRec O0 = load_off(base + 2);
    OffRec O1 = load_off(base + 3);

#pragma unroll 2
    for (int ls = 0; ls < 9; ++ls) {
        const int s = base + ls;
        const ushort_t* wp = wdp + (((size_t)(s << 2) * 64) + lane) * 8;
        bf16x8 a0 = *(const bf16x8*)(wp);
        bf16x8 a1 = *(const bf16x8*)(wp + 512);
        bf16x8 a2 = *(const bf16x8*)(wp + 1024);
        bf16x8 a3 = *(const bf16x8*)(wp + 1536);

        Stage cur = (ls & 1) ? P1 : P0;
        bf16x8 bfrag;
        {
            const int* c00 = (const int*)&cur.g0; const int* c01 = (const int*)&cur.g1;
            const int* c10 = (const int*)&cur.g2; const int* c11 = (const int*)&cur.g3;
#pragma unroll
            for (int j = 0; j < 4; ++j) {
                float lo = cur.w0 * bf_lo(c00[j]) + cur.w1 * bf_lo(c01[j])
                         + cur.w2 * bf_lo(c10[j]) + cur.w3 * bf_lo(c11[j]);
                float hv = cur.w0 * bf_hi(c00[j]) + cur.w1 * bf_hi(c01[j])
                         + cur.w2 * bf_hi(c10[j]) + cur.w3 * bf_hi(c11[j]);
                bfrag[2 * j]     = (__bf16)lo;
                bfrag[2 * j + 1] = (__bf16)hv;
            }
        }

        int s2 = base + min(ls + 2, 8);
        if (ls & 1) P1 = sample(s2, O1); else P0 = sample(s2, O0);
        int s4 = base + min(ls + 4, 8);
        if (ls & 1) O1 = load_off(s4); else O0 = load_off(s4);

        acc0 = __builtin_amdgcn_mfma_f32_16x16x32_bf16(a0, bfrag, acc0, 0, 0, 0);
        acc1 = __builtin_amdgcn_mfma_f32_16x16x32_bf16(a1, bfrag, acc1, 0, 0, 0);
        acc2 = __builtin_amdgcn_mfma_f32_16x16x32_bf16(a2, bfrag, acc2, 0, 0, 0);
        acc3 = __builtin_amdgcn_mfma_f32_16x16x32_bf16(a3, bfrag, acc3, 0, 0, 0);
    }

    const int ocr = hi4 << 2;
    const size_t pbase = (size_t)b * C_ * HW_ + (size_t)y * W_ + x0 + l15;
    if (kh == 0) {
#pragma unroll
        for (int r = 0; r < 4; ++r) {
            int oc0 = ocr + r;
            outp[pbase + (size_t)(oc0)      * HW_] = acc0[r] + bd[oc0];
            outp[pbase + (size_t)(oc0 + 16) * HW_] = acc1[r] + bd[oc0 + 16];
            outp[pbase + (size_t)(oc0 + 32) * HW_] = acc2[r] + bd[oc0 + 32];
            outp[pbase + (size_t)(oc0 + 48) * HW_] = acc3[r] + bd[oc0 + 48];
        }
    } else {
#pragma unroll
        for (int r = 0; r < 4; ++r) {
            int oc0 = ocr + r;
            partial[pbase + (size_t)(oc0)      * HW_] = f2bf(acc0[r]);
            partial[pbase + (size_t)(oc0 + 16) * HW_] = f2bf(acc1[r]);
            partial[pbase + (size_t)(oc0 + 32) * HW_] = f2bf(acc2[r]);
            partial[pbase + (size_t)(oc0 + 48) * HW_] = f2bf(acc3[r]);
        }
    }
}

// ---------------------------------------------------------------------------
// combine: out += bf16 partial (8 elems/thread). grid 1920.
// ---------------------------------------------------------------------------
__global__ __launch_bounds__(256) void combine_half(
    float* __restrict__ outp, const ushort_t* __restrict__ part)
{
    size_t t = (size_t)(blockIdx.x * 256 + threadIdx.x) * 8;
    int4 p = *(const int4*)&part[t];
    const ushort_t* pu = (const ushort_t*)&p;
    float4 a = *(float4*)&outp[t];
    float4 c = *(float4*)&outp[t + 4];
    a.x += bf2f(pu[0]); a.y += bf2f(pu[1]); a.z += bf2f(pu[2]); a.w += bf2f(pu[3]);
    c.x += bf2f(pu[4]); c.y += bf2f(pu[5]); c.z += bf2f(pu[6]); c.w += bf2f(pu[7]);
    *(float4*)&outp[t] = a;
    *(float4*)&outp[t + 4] = c;
}

// ---------------------------------------------------------------------------
extern "C" void kernel_launch(void* const* d_in, const int* in_sizes, int n_in,
                              void* d_out, int out_size, void* d_ws, size_t ws_size,
                              hipStream_t stream)
{
    const float* nbr = (const float*)d_in[0];
    const float* ref = (const float*)d_in[1];
    const float* w1  = (const float*)d_in[2];
    const float* b1  = (const float*)d_in[3];
    const float* w2  = (const float*)d_in[4];
    const float* b2  = (const float*)d_in[5];
    const float* wd  = (const float*)d_in[6];
    const float* bd  = (const float*)d_in[7];

    float* out     = (float*)d_out;
    float* off_out = out + ALIGNED_SZ;

    char* ws = (char*)d_ws;
    ushort_t* w1pf  = (ushort_t*)(ws + W1P_OFF);
    ushort_t* w2pf  = (ushort_t*)(ws + W2P_OFF);
    ushort_t* pin   = (ushort_t*)(ws + PIN_OFF);
    ushort_t* hbufp = (ushort_t*)(ws + HBUF_OFF);   // conv1 out; dconv partial
    ushort_t* maskp = (ushort_t*)(ws + MASK_OFF);
    ushort_t* wdp   = (ushort_t*)(ws + WDP_OFF);

    dim3 blk(256, 1, 1);
    pack_weights<<<1008, blk, 0, stream>>>(w1, w2, wd, w1pf, w2pf, wdp);
    pack_input<<<3840, blk, 0, stream>>>(nbr, ref, pin);
    conv1_mfma<<<dim3(5, 128, 2), blk, 0, stream>>>(pin, b1, w1pf, hbufp);
    conv2_mfma<<<dim3(5, 128, 8), blk, 0, stream>>>(hbufp, b2, w2pf, off_out, maskp);
    dconv_mfma<<<1920, blk, 0, stream>>>(pin, off_out, maskp, wdp, bd, out, hbufp);
    combine_half<<<1920, blk, 0, stream>>>(out, hbufp);
}

// Round 16
// 140.847 us; speedup vs baseline: 1.3620x; 1.3620x over previous
//
#include <hip/hip_runtime.h>
#include <cstdint>
#include <cmath>

#define B_ 2
#define C_ 64
#define H_ 128
#define W_ 240
#define HW_ (H_*W_)
#define OFF_CH 144
#define MASK_CH 72
#define ALIGNED_SZ (B_*C_*HW_)   /* 3932160 floats */

typedef __bf16 bf16x8 __attribute__((ext_vector_type(8)));
typedef float f32x4 __attribute__((ext_vector_type(4)));
typedef short short4v __attribute__((ext_vector_type(4)));
typedef unsigned short ushort_t;

__device__ __forceinline__ ushort_t f2bf(float f) {
    unsigned u = __float_as_uint(f);
    u += 0x7fffu + ((u >> 16) & 1u);          // round-to-nearest-even
    return (ushort_t)(u >> 16);
}
__device__ __forceinline__ float bf2f(ushort_t b) {
    return __uint_as_float((unsigned)b << 16);
}
__device__ __forceinline__ float bf_lo(int q) {
    return __uint_as_float((unsigned)q << 16);
}
__device__ __forceinline__ float bf_hi(int q) {
    return __uint_as_float((unsigned)q & 0xffff0000u);
}

// workspace layout (byte offsets); total 32,956,416 B
// pin: nbr half = 8 per-dg planes [dg][HW][8ch]; ref half = [HW][64].
// HBUF region is DEAD after conv2 -> reused as dconv khalf-1 bf16 partial.
#define W1P_OFF  0u
#define W2P_OFF  147456u
#define PIN_OFF  442368u      /* [B][2][HW][64] bf16 = 15,728,640 */
#define HBUF_OFF 16171008u    /* [B][H][W][64]  bf16 =  7,864,320 */
#define MASK_OFF 24035328u    /* [B][72][H][W]  bf16 =  8,847,360 */
#define WDP_OFF  32882688u    /* [18][4][64][8] bf16 =     73,728 */

// ---------------------------------------------------------------------------
// Repack all weights into MFMA A-fragment layouts (unchanged, proven).
// ---------------------------------------------------------------------------
__global__ __launch_bounds__(256) void pack_weights(
    const float* __restrict__ w1, const float* __restrict__ w2,
    const float* __restrict__ wd,
    ushort_t* __restrict__ w1pf, ushort_t* __restrict__ w2pf,
    ushort_t* __restrict__ wdp)
{
    int t = blockIdx.x * 256 + threadIdx.x;
    if (t < 73728) {
        int j = t & 7, lane = (t >> 3) & 63, r = t >> 9;
        int wv = r & 3, ct = r >> 2;
        int tap = ct % 9, chunk = ct / 9;
        int oc = wv * 16 + (lane & 15);
        int ci = chunk * 32 + ((lane >> 4) << 3) + j;
        w1pf[t] = f2bf(w1[((size_t)oc * 128 + ci) * 9 + tap]);
    } else if (t < 73728 + 147456) {
        int f = t - 73728;
        int j = f & 7, lane = (f >> 3) & 63, r = f >> 9;
        int wv = r & 3, q = r >> 2;
        int tap = q % 9, oc2 = q / 9;
        int chunk = oc2 & 1, ocg = oc2 >> 1;
        int oc = ocg * 64 + wv * 16 + (lane & 15);
        int ci = chunk * 32 + ((lane >> 4) << 3) + j;
        float v = (oc < 216) ? w2[((size_t)oc * 64 + ci) * 9 + tap] : 0.f;
        w2pf[f] = f2bf(v);
    } else if (t < 73728 + 147456 + 36864) {
        int f = t - 221184;
        int j = f & 7, lane = (f >> 3) & 63, sg = f >> 9;
        int g = sg & 3, s = sg >> 2;
        int oc = g * 16 + (lane & 15);
        int K = s * 32 + ((lane >> 4) << 3) + j;
        int dg = K / 72, rr = K - dg * 72;
        int tap = rr >> 3, ci = (dg << 3) + (rr & 7);
        wdp[f] = f2bf(wd[((size_t)oc * 64 + ci) * 9 + tap]);
    }
}

// ---------------------------------------------------------------------------
// Repack input. nbr -> per-dg planes [b][dg][HW][8]; ref -> [b][HW][64].
// ---------------------------------------------------------------------------
__global__ __launch_bounds__(256) void pack_input(
    const float* __restrict__ nbr, const float* __restrict__ ref,
    ushort_t* __restrict__ pin)
{
    int f = blockIdx.x * 256 + threadIdx.x;    // < 983040 = B*HW*16
    int civec = f & 15;
    int rem = f >> 4;                          // b*HW + pix
    int b = rem / HW_, pix = rem - b * HW_;
    const int half = civec >> 3;
    const float* src = (half == 0) ? (nbr + (size_t)b * 64 * HW_)
                                   : (ref + (size_t)b * 64 * HW_);
    int cbase = (civec & 7) * 8;
    union { ushort_t u[8]; int4 v; } o;
#pragma unroll
    for (int j = 0; j < 8; ++j)
        o.u[j] = f2bf(src[(size_t)(cbase + j) * HW_ + pix]);
    size_t dst;
    if (half == 0) {    // dg-plane layout: dg = civec&7
        dst = (size_t)b * 2 * HW_ * 64 + (size_t)(civec & 7) * HW_ * 8 + (size_t)pix * 8;
    } else {            // ref half: [HW][64]
        dst = ((size_t)(b * 2 + 1) * HW_ + pix) * 64 + cbase;
    }
    *(int4*)&pin[dst] = o.v;
}

// ---------------------------------------------------------------------------
// conv1 via MFMA implicit GEMM (round-11 proven version, 1 row/block).
// ---------------------------------------------------------------------------
__global__ __launch_bounds__(256) void conv1_mfma(
    const ushort_t* __restrict__ pin, const float* __restrict__ b1,
    const ushort_t* __restrict__ w1pf, ushort_t* __restrict__ hbuf)
{
    const int bx = blockIdx.x, y = blockIdx.y, b = blockIdx.z;
    const int x0 = bx * 48;
    const int tid = threadIdx.x;
    const int wv = tid >> 6, lane = tid & 63;
    const int l15 = lane & 15, k8 = (lane >> 4) << 3;

    __shared__ __align__(16) ushort_t s_in[3 * 50 * 40];

    f32x4 acc[3];
#pragma unroll
    for (int i = 0; i < 3; ++i) acc[i] = (f32x4){0.f, 0.f, 0.f, 0.f};

    for (int chunk = 0; chunk < 4; ++chunk) {
        const int ci0 = chunk << 5;
        for (int i = tid; i < 600; i += 256) {
            int cvec = i & 3, rc = i >> 2;
            int row = rc / 50, col = rc - row * 50;
            int gy = y + row - 1, gx = x0 + col - 1;
            int ci = ci0 + cvec * 8;
            int half = ci >> 6, cw = ci & 63;
            int4 v = {0, 0, 0, 0};
            if ((unsigned)gy < (unsigned)H_ && (unsigned)gx < (unsigned)W_) {
                size_t srca;
                if (half == 0)
                    srca = (size_t)b * 2 * HW_ * 64 + (size_t)(cw >> 3) * HW_ * 8
                         + (size_t)(gy * W_ + gx) * 8;
                else
                    srca = ((size_t)(b * 2 + 1) * HW_ + (size_t)gy * W_ + gx) * 64 + cw;
                v = *(const int4*)&pin[srca];
            }
            *(int4*)&s_in[(row * 50 + col) * 40 + cvec * 8] = v;
        }
        bf16x8 af[9];
#pragma unroll
        for (int tap = 0; tap < 9; ++tap)
            af[tap] = *(const bf16x8*)&w1pf[((((size_t)chunk * 9 + tap) * 4 + wv) * 64 + lane) * 8];
        __syncthreads();

#pragma unroll
        for (int tap = 0; tap < 9; ++tap) {
            const int ky = tap / 3, kx = tap - ky * 3;
#pragma unroll
            for (int pt = 0; pt < 3; ++pt) {
                int col = (pt << 4) + l15 + kx;
                bf16x8 bb = *(const bf16x8*)&s_in[(ky * 50 + col) * 40 + k8];
                acc[pt] = __builtin_amdgcn_mfma_f32_16x16x32_bf16(af[tap], bb, acc[pt], 0, 0, 0);
            }
        }
        __syncthreads();
    }

    const int ocb = (wv << 4) + ((lane >> 4) << 2);
    float bias[4];
#pragma unroll
    for (int r = 0; r < 4; ++r) bias[r] = b1[ocb + r];
#pragma unroll
    for (int pt = 0; pt < 3; ++pt) {
        int gx = x0 + (pt << 4) + l15;
        union { ushort_t u[4]; short4v s; } o;
#pragma unroll
        for (int r = 0; r < 4; ++r) {
            float v = acc[pt][r] + bias[r];
            v = (v >= 0.f) ? v : 0.1f * v;
            o.u[r] = f2bf(v);
        }
        *(short4v*)&hbuf[(((size_t)b * H_ + y) * W_ + gx) * 64 + ocb] = o.s;
    }
}

// ---------------------------------------------------------------------------
// conv2 (round-11 proven version: 1 row, 1 oc-group per block).
// grid (5, 128, 8), z = b*4 + ocg.  Best of the 1/2/4-ocg family.
// ---------------------------------------------------------------------------
__global__ __launch_bounds__(256) void conv2_mfma(
    const ushort_t* __restrict__ hbuf, const float* __restrict__ b2,
    const ushort_t* __restrict__ w2pf,
    float* __restrict__ off_out, ushort_t* __restrict__ maskbuf)
{
    const int bx = blockIdx.x, y = blockIdx.y;
    const int b = blockIdx.z >> 2, ocg = blockIdx.z & 3;
    const int x0 = bx * 48;
    const int tid = threadIdx.x;
    const int wv = tid >> 6, lane = tid & 63;
    const int l15 = lane & 15, k8 = (lane >> 4) << 3;

    __shared__ __align__(16) ushort_t s_in[3 * 50 * 40];

    f32x4 acc[3];
#pragma unroll
    for (int i = 0; i < 3; ++i) acc[i] = (f32x4){0.f, 0.f, 0.f, 0.f};

    for (int chunk = 0; chunk < 2; ++chunk) {
        const int ci0 = chunk << 5;
        for (int i = tid; i < 600; i += 256) {
            int cvec = i & 3, rc = i >> 2;
            int row = rc / 50, col = rc - row * 50;
            int gy = y + row - 1, gx = x0 + col - 1;
            int4 v = {0, 0, 0, 0};
            if ((unsigned)gy < (unsigned)H_ && (unsigned)gx < (unsigned)W_)
                v = *(const int4*)&hbuf[(((size_t)b * H_ + gy) * W_ + gx) * 64 + ci0 + cvec * 8];
            *(int4*)&s_in[(row * 50 + col) * 40 + cvec * 8] = v;
        }
        bf16x8 af[9];
#pragma unroll
        for (int tap = 0; tap < 9; ++tap)
            af[tap] = *(const bf16x8*)&w2pf[(((((size_t)ocg * 2 + chunk) * 9 + tap) * 4 + wv) * 64 + lane) * 8];
        __syncthreads();

#pragma unroll
        for (int tap = 0; tap < 9; ++tap) {
            const int ky = tap / 3, kx = tap - ky * 3;
#pragma unroll
            for (int pt = 0; pt < 3; ++pt) {
                int col = (pt << 4) + l15 + kx;
                bf16x8 bb = *(const bf16x8*)&s_in[(ky * 50 + col) * 40 + k8];
                acc[pt] = __builtin_amdgcn_mfma_f32_16x16x32_bf16(af[tap], bb, acc[pt], 0, 0, 0);
            }
        }
        __syncthreads();
    }

    const int ocb = (wv << 4) + ((lane >> 4) << 2);
#pragma unroll
    for (int pt = 0; pt < 3; ++pt) {
        int gx = x0 + (pt << 4) + l15;
#pragma unroll
        for (int r = 0; r < 4; ++r) {
            int co = (ocg << 6) + ocb + r;
            if (co < 216) {
                float v = acc[pt][r] + b2[co];
                if (co < 144) {
                    off_out[((size_t)b * OFF_CH + co) * HW_ + y * W_ + gx] = v;
                } else {
                    maskbuf[((size_t)b * MASK_CH + (co - 144)) * HW_ + y * W_ + gx] =
                        f2bf(1.f / (1.f + expf(-v)));
                }
            }
        }
    }
}

// ---------------------------------------------------------------------------
// dconv v9 (round-12 proven): barrier-free ping-pong + split-K x2.
// __launch_bounds__(256,4): 4 waves/EU -> 128 VGPR/wave budget. (256,8)
// capped the budget at 64 VGPR and spilled the whole pipeline (round 15:
// WRITE_SIZE 23->200 MB, dur 48->120 us). Do not raise again.
// ---------------------------------------------------------------------------
struct OffRec { float dy, dx, m; };
struct Stage  { int4 g0, g1, g2, g3; float w0, w1, w2, w3; };

__global__ __launch_bounds__(256, 4) void dconv_mfma(
    const ushort_t* __restrict__ pin,
    const float* __restrict__ offs,
    const ushort_t* __restrict__ maskbuf,
    const ushort_t* __restrict__ wdp, const float* __restrict__ bd,
    float* __restrict__ outp, ushort_t* __restrict__ partial)
{
    const int bid = blockIdx.x;
    const int kh  = (bid >= 960) ? 1 : 0;
    const int sb  = bid - kh * 960;
    const int nid = (sb & 7) * 120 + (sb >> 3);
    const int b   = nid / 480;
    const int rr_ = nid - b * 480;
    const int byt = rr_ / 15, bxt = rr_ - byt * 15;   // byt 0..31
    const int x0 = bxt << 4, y0 = byt << 2;
    const int base = kh * 9;                          // slice base

    const int tid = threadIdx.x;
    const int wv = tid >> 6, lane = tid & 63;
    const int l15 = lane & 15, hi4 = lane >> 4;       // hi4 = k-group

    const int x = x0 + l15, y = y0 + wv;              // this lane's pixel
    const size_t pix = (size_t)y * W_ + x;
    const size_t pinb = (size_t)b * 2 * HW_ * 64;     // nbr dg-planes base
    const float* offp = offs + (size_t)b * OFF_CH * HW_ + pix;
    const ushort_t* mkp = maskbuf + (size_t)b * MASK_CH * HW_ + pix;

    f32x4 acc0 = {0.f,0.f,0.f,0.f}, acc1 = {0.f,0.f,0.f,0.f};
    f32x4 acc2 = {0.f,0.f,0.f,0.f}, acc3 = {0.f,0.f,0.f,0.f};

    auto load_off = [&](int s) -> OffRec {
        int K = (s << 5) + (hi4 << 3);
        int dg = K / 72, r2 = K - dg * 72, tap = r2 >> 3;
        OffRec o;
        o.dy = offp[(size_t)(dg * 18 + tap) * HW_];
        o.dx = offp[(size_t)(dg * 18 + 9 + tap) * HW_];
        o.m  = bf2f(mkp[(size_t)(dg * 9 + tap) * HW_]);
        return o;
    };
    auto sample = [&](int s, OffRec of) -> Stage {
        int K = (s << 5) + (hi4 << 3);
        int dg = K / 72, rm = K - dg * 72, tap = rm >> 3;
        int ky = tap / 3 - 1, kx = tap % 3 - 1;
        float py  = (float)(y + ky) + of.dy;
        float pxf = (float)(x + kx) + of.dx;
        float yf = floorf(py), xf = floorf(pxf);
        float wy = py - yf, wx = pxf - xf;
        int yi = (int)yf, xi = (int)xf;
        bool y0v = (unsigned)yi < (unsigned)H_;
        bool y1v = (unsigned)(yi + 1) < (unsigned)H_;
        bool x0v = (unsigned)xi < (unsigned)W_;
        bool x1v = (unsigned)(xi + 1) < (unsigned)W_;
        Stage st;
        st.w0 = (y0v && x0v) ? (1.f - wy) * (1.f - wx) * of.m : 0.f;
        st.w1 = (y0v && x1v) ? (1.f - wy) * wx         * of.m : 0.f;
        st.w2 = (y1v && x0v) ? wy         * (1.f - wx) * of.m : 0.f;
        st.w3 = (y1v && x1v) ? wy         * wx         * of.m : 0.f;
        int yc0 = min(max(yi, 0), H_ - 1), yc1 = min(max(yi + 1, 0), H_ - 1);
        int xc0 = min(max(xi, 0), W_ - 1), xc1 = min(max(xi + 1, 0), W_ - 1);
        const size_t dgb = pinb + (size_t)dg * HW_ * 8;   // 16B px records
        st.g0 = *(const int4*)&pin[dgb + (size_t)(yc0 * W_ + xc0) * 8];
        st.g1 = *(const int4*)&pin[dgb + (size_t)(yc0 * W_ + xc1) * 8];
        st.g2 = *(const int4*)&pin[dgb + (size_t)(yc1 * W_ + xc0) * 8];
        st.g3 = *(const int4*)&pin[dgb + (size_t)(yc1 * W_ + xc1) * 8];
        return st;
    };

    // ---- prologue: stages for local slices 0,1; offsets for 2,3 ----
    Stage  P0 = sample(base + 0, load_off(base + 0));
    Stage  P1 = sample(base + 1, load_off(base + 1));
    OffRec O0 = load_off(base + 2);
    OffRec O1 = load_off(base + 3);

#pragma unroll 2
    for (int ls = 0; ls < 9; ++ls) {
        const int s = base + ls;
        const ushort_t* wp = wdp + (((size_t)(s << 2) * 64) + lane) * 8;
        bf16x8 a0 = *(const bf16x8*)(wp);
        bf16x8 a1 = *(const bf16x8*)(wp + 512);
        bf16x8 a2 = *(const bf16x8*)(wp + 1024);
        bf16x8 a3 = *(const bf16x8*)(wp + 1536);

        Stage cur = (ls & 1) ? P1 : P0;
        bf16x8 bfrag;
        {
            const int* c00 = (const int*)&cur.g0; const int* c01 = (const int*)&cur.g1;
            const int* c10 = (const int*)&cur.g2; const int* c11 = (const int*)&cur.g3;
#pragma unroll
            for (int j = 0; j < 4; ++j) {
                float lo = cur.w0 * bf_lo(c00[j]) + cur.w1 * bf_lo(c01[j])
                         + cur.w2 * bf_lo(c10[j]) + cur.w3 * bf_lo(c11[j]);
                float hv = cur.w0 * bf_hi(c00[j]) + cur.w1 * bf_hi(c01[j])
                         + cur.w2 * bf_hi(c10[j]) + cur.w3 * bf_hi(c11[j]);
                bfrag[2 * j]     = (__bf16)lo;
                bfrag[2 * j + 1] = (__bf16)hv;
            }
        }

        int s2 = base + min(ls + 2, 8);
        if (ls & 1) P1 = sample(s2, O1); else P0 = sample(s2, O0);
        int s4 = base + min(ls + 4, 8);
        if (ls & 1) O1 = load_off(s4); else O0 = load_off(s4);

        acc0 = __builtin_amdgcn_mfma_f32_16x16x32_bf16(a0, bfrag, acc0, 0, 0, 0);
        acc1 = __builtin_amdgcn_mfma_f32_16x16x32_bf16(a1, bfrag, acc1, 0, 0, 0);
        acc2 = __builtin_amdgcn_mfma_f32_16x16x32_bf16(a2, bfrag, acc2, 0, 0, 0);
        acc3 = __builtin_amdgcn_mfma_f32_16x16x32_bf16(a3, bfrag, acc3, 0, 0, 0);
    }

    const int ocr = hi4 << 2;
    const size_t pbase = (size_t)b * C_ * HW_ + (size_t)y * W_ + x0 + l15;
    if (kh == 0) {
#pragma unroll
        for (int r = 0; r < 4; ++r) {
            int oc0 = ocr + r;
            outp[pbase + (size_t)(oc0)      * HW_] = acc0[r] + bd[oc0];
            outp[pbase + (size_t)(oc0 + 16) * HW_] = acc1[r] + bd[oc0 + 16];
            outp[pbase + (size_t)(oc0 + 32) * HW_] = acc2[r] + bd[oc0 + 32];
            outp[pbase + (size_t)(oc0 + 48) * HW_] = acc3[r] + bd[oc0 + 48];
        }
    } else {
#pragma unroll
        for (int r = 0; r < 4; ++r) {
            int oc0 = ocr + r;
            partial[pbase + (size_t)(oc0)      * HW_] = f2bf(acc0[r]);
            partial[pbase + (size_t)(oc0 + 16) * HW_] = f2bf(acc1[r]);
            partial[pbase + (size_t)(oc0 + 32) * HW_] = f2bf(acc2[r]);
            partial[pbase + (size_t)(oc0 + 48) * HW_] = f2bf(acc3[r]);
        }
    }
}

// ---------------------------------------------------------------------------
// combine: out += bf16 partial (8 elems/thread). grid 1920.
// ---------------------------------------------------------------------------
__global__ __launch_bounds__(256) void combine_half(
    float* __restrict__ outp, const ushort_t* __restrict__ part)
{
    size_t t = (size_t)(blockIdx.x * 256 + threadIdx.x) * 8;
    int4 p = *(const int4*)&part[t];
    const ushort_t* pu = (const ushort_t*)&p;
    float4 a = *(float4*)&outp[t];
    float4 c = *(float4*)&outp[t + 4];
    a.x += bf2f(pu[0]); a.y += bf2f(pu[1]); a.z += bf2f(pu[2]); a.w += bf2f(pu[3]);
    c.x += bf2f(pu[4]); c.y += bf2f(pu[5]); c.z += bf2f(pu[6]); c.w += bf2f(pu[7]);
    *(float4*)&outp[t] = a;
    *(float4*)&outp[t + 4] = c;
}

// ---------------------------------------------------------------------------
extern "C" void kernel_launch(void* const* d_in, const int* in_sizes, int n_in,
                              void* d_out, int out_size, void* d_ws, size_t ws_size,
                              hipStream_t stream)
{
    const float* nbr = (const float*)d_in[0];
    const float* ref = (const float*)d_in[1];
    const float* w1  = (const float*)d_in[2];
    const float* b1  = (const float*)d_in[3];
    const float* w2  = (const float*)d_in[4];
    const float* b2  = (const float*)d_in[5];
    const float* wd  = (const float*)d_in[6];
    const float* bd  = (const float*)d_in[7];

    float* out     = (float*)d_out;
    float* off_out = out + ALIGNED_SZ;

    char* ws = (char*)d_ws;
    ushort_t* w1pf  = (ushort_t*)(ws + W1P_OFF);
    ushort_t* w2pf  = (ushort_t*)(ws + W2P_OFF);
    ushort_t* pin   = (ushort_t*)(ws + PIN_OFF);
    ushort_t* hbufp = (ushort_t*)(ws + HBUF_OFF);   // conv1 out; dconv partial
    ushort_t* maskp = (ushort_t*)(ws + MASK_OFF);
    ushort_t* wdp   = (ushort_t*)(ws + WDP_OFF);

    dim3 blk(256, 1, 1);
    pack_weights<<<1008, blk, 0, stream>>>(w1, w2, wd, w1pf, w2pf, wdp);
    pack_input<<<3840, blk, 0, stream>>>(nbr, ref, pin);
    conv1_mfma<<<dim3(5, 128, 2), blk, 0, stream>>>(pin, b1, w1pf, hbufp);
    conv2_mfma<<<dim3(5, 128, 8), blk, 0, stream>>>(hbufp, b2, w2pf, off_out, maskp);
    dconv_mfma<<<1920, blk, 0, stream>>>(pin, off_out, maskp, wdp, bd, out, hbufp);
    combine_half<<<1920, blk, 0, stream>>>(out, hbufp);
}

// Round 17
// 138.485 us; speedup vs baseline: 1.3853x; 1.0171x over previous
//
#include <hip/hip_runtime.h>
#include <cstdint>
#include <cmath>

#define B_ 2
#define C_ 64
#define H_ 128
#define W_ 240
#define HW_ (H_*W_)
#define OFF_CH 144
#define MASK_CH 72
#define ALIGNED_SZ (B_*C_*HW_)   /* 3932160 floats */

typedef __bf16 bf16x8 __attribute__((ext_vector_type(8)));
typedef float f32x4 __attribute__((ext_vector_type(4)));
typedef short short4v __attribute__((ext_vector_type(4)));
typedef unsigned short ushort_t;

__device__ __forceinline__ ushort_t f2bf(float f) {
    unsigned u = __float_as_uint(f);
    u += 0x7fffu + ((u >> 16) & 1u);          // round-to-nearest-even
    return (ushort_t)(u >> 16);
}
__device__ __forceinline__ float bf2f(ushort_t b) {
    return __uint_as_float((unsigned)b << 16);
}
__device__ __forceinline__ float bf_lo(int q) {
    return __uint_as_float((unsigned)q << 16);
}
__device__ __forceinline__ float bf_hi(int q) {
    return __uint_as_float((unsigned)q & 0xffff0000u);
}

// workspace layout (byte offsets); total 32,956,416 B
// pin: nbr half = 8 per-dg planes [dg][HW][8ch]; ref half = [HW][64].
#define W1P_OFF  0u
#define W2P_OFF  147456u
#define PIN_OFF  442368u      /* [B][2][HW][64] bf16 = 15,728,640 */
#define HBUF_OFF 16171008u    /* [B][H][W][64]  bf16 =  7,864,320 */
#define MASK_OFF 24035328u    /* [B][72][H][W]  bf16 =  8,847,360 */
#define WDP_OFF  32882688u    /* [18][4][64][8] bf16 =     73,728 */

// ---------------------------------------------------------------------------
// Repack all weights into MFMA A-fragment layouts (proven).
// ---------------------------------------------------------------------------
__global__ __launch_bounds__(256) void pack_weights(
    const float* __restrict__ w1, const float* __restrict__ w2,
    const float* __restrict__ wd,
    ushort_t* __restrict__ w1pf, ushort_t* __restrict__ w2pf,
    ushort_t* __restrict__ wdp)
{
    int t = blockIdx.x * 256 + threadIdx.x;
    if (t < 73728) {
        int j = t & 7, lane = (t >> 3) & 63, r = t >> 9;
        int wv = r & 3, ct = r >> 2;
        int tap = ct % 9, chunk = ct / 9;
        int oc = wv * 16 + (lane & 15);
        int ci = chunk * 32 + ((lane >> 4) << 3) + j;
        w1pf[t] = f2bf(w1[((size_t)oc * 128 + ci) * 9 + tap]);
    } else if (t < 73728 + 147456) {
        int f = t - 73728;
        int j = f & 7, lane = (f >> 3) & 63, r = f >> 9;
        int wv = r & 3, q = r >> 2;
        int tap = q % 9, oc2 = q / 9;
        int chunk = oc2 & 1, ocg = oc2 >> 1;
        int oc = ocg * 64 + wv * 16 + (lane & 15);
        int ci = chunk * 32 + ((lane >> 4) << 3) + j;
        float v = (oc < 216) ? w2[((size_t)oc * 64 + ci) * 9 + tap] : 0.f;
        w2pf[f] = f2bf(v);
    } else if (t < 73728 + 147456 + 36864) {
        int f = t - 221184;
        int j = f & 7, lane = (f >> 3) & 63, sg = f >> 9;
        int g = sg & 3, s = sg >> 2;
        int oc = g * 16 + (lane & 15);
        int K = s * 32 + ((lane >> 4) << 3) + j;
        int dg = K / 72, rr = K - dg * 72;
        int tap = rr >> 3, ci = (dg << 3) + (rr & 7);
        wdp[f] = f2bf(wd[((size_t)oc * 64 + ci) * 9 + tap]);
    }
}

// ---------------------------------------------------------------------------
// Repack input. nbr -> per-dg planes [b][dg][HW][8]; ref -> [b][HW][64].
// ---------------------------------------------------------------------------
__global__ __launch_bounds__(256) void pack_input(
    const float* __restrict__ nbr, const float* __restrict__ ref,
    ushort_t* __restrict__ pin)
{
    int f = blockIdx.x * 256 + threadIdx.x;    // < 983040 = B*HW*16
    int civec = f & 15;
    int rem = f >> 4;                          // b*HW + pix
    int b = rem / HW_, pix = rem - b * HW_;
    const int half = civec >> 3;
    const float* src = (half == 0) ? (nbr + (size_t)b * 64 * HW_)
                                   : (ref + (size_t)b * 64 * HW_);
    int cbase = (civec & 7) * 8;
    union { ushort_t u[8]; int4 v; } o;
#pragma unroll
    for (int j = 0; j < 8; ++j)
        o.u[j] = f2bf(src[(size_t)(cbase + j) * HW_ + pix]);
    size_t dst;
    if (half == 0) {    // dg-plane layout: dg = civec&7
        dst = (size_t)b * 2 * HW_ * 64 + (size_t)(civec & 7) * HW_ * 8 + (size_t)pix * 8;
    } else {            // ref half: [HW][64]
        dst = ((size_t)(b * 2 + 1) * HW_ + pix) * 64 + cbase;
    }
    *(int4*)&pin[dst] = o.v;
}

// ---------------------------------------------------------------------------
// conv1 via MFMA implicit GEMM (round-11 proven version, 1 row/block).
// ---------------------------------------------------------------------------
__global__ __launch_bounds__(256) void conv1_mfma(
    const ushort_t* __restrict__ pin, const float* __restrict__ b1,
    const ushort_t* __restrict__ w1pf, ushort_t* __restrict__ hbuf)
{
    const int bx = blockIdx.x, y = blockIdx.y, b = blockIdx.z;
    const int x0 = bx * 48;
    const int tid = threadIdx.x;
    const int wv = tid >> 6, lane = tid & 63;
    const int l15 = lane & 15, k8 = (lane >> 4) << 3;

    __shared__ __align__(16) ushort_t s_in[3 * 50 * 40];

    f32x4 acc[3];
#pragma unroll
    for (int i = 0; i < 3; ++i) acc[i] = (f32x4){0.f, 0.f, 0.f, 0.f};

    for (int chunk = 0; chunk < 4; ++chunk) {
        const int ci0 = chunk << 5;
        for (int i = tid; i < 600; i += 256) {
            int cvec = i & 3, rc = i >> 2;
            int row = rc / 50, col = rc - row * 50;
            int gy = y + row - 1, gx = x0 + col - 1;
            int ci = ci0 + cvec * 8;
            int half = ci >> 6, cw = ci & 63;
            int4 v = {0, 0, 0, 0};
            if ((unsigned)gy < (unsigned)H_ && (unsigned)gx < (unsigned)W_) {
                size_t srca;
                if (half == 0)
                    srca = (size_t)b * 2 * HW_ * 64 + (size_t)(cw >> 3) * HW_ * 8
                         + (size_t)(gy * W_ + gx) * 8;
                else
                    srca = ((size_t)(b * 2 + 1) * HW_ + (size_t)gy * W_ + gx) * 64 + cw;
                v = *(const int4*)&pin[srca];
            }
            *(int4*)&s_in[(row * 50 + col) * 40 + cvec * 8] = v;
        }
        bf16x8 af[9];
#pragma unroll
        for (int tap = 0; tap < 9; ++tap)
            af[tap] = *(const bf16x8*)&w1pf[((((size_t)chunk * 9 + tap) * 4 + wv) * 64 + lane) * 8];
        __syncthreads();

#pragma unroll
        for (int tap = 0; tap < 9; ++tap) {
            const int ky = tap / 3, kx = tap - ky * 3;
#pragma unroll
            for (int pt = 0; pt < 3; ++pt) {
                int col = (pt << 4) + l15 + kx;
                bf16x8 bb = *(const bf16x8*)&s_in[(ky * 50 + col) * 40 + k8];
                acc[pt] = __builtin_amdgcn_mfma_f32_16x16x32_bf16(af[tap], bb, acc[pt], 0, 0, 0);
            }
        }
        __syncthreads();
    }

    const int ocb = (wv << 4) + ((lane >> 4) << 2);
    float bias[4];
#pragma unroll
    for (int r = 0; r < 4; ++r) bias[r] = b1[ocb + r];
#pragma unroll
    for (int pt = 0; pt < 3; ++pt) {
        int gx = x0 + (pt << 4) + l15;
        union { ushort_t u[4]; short4v s; } o;
#pragma unroll
        for (int r = 0; r < 4; ++r) {
            float v = acc[pt][r] + bias[r];
            v = (v >= 0.f) ? v : 0.1f * v;
            o.u[r] = f2bf(v);
        }
        *(short4v*)&hbuf[(((size_t)b * H_ + y) * W_ + gx) * 64 + ocb] = o.s;
    }
}

// ---------------------------------------------------------------------------
// conv2 (round-11 proven version: 1 row, 1 oc-group per block).
// grid (5, 128, 8), z = b*4 + ocg.  Best of the 1/2/4-ocg family.
// ---------------------------------------------------------------------------
__global__ __launch_bounds__(256) void conv2_mfma(
    const ushort_t* __restrict__ hbuf, const float* __restrict__ b2,
    const ushort_t* __restrict__ w2pf,
    float* __restrict__ off_out, ushort_t* __restrict__ maskbuf)
{
    const int bx = blockIdx.x, y = blockIdx.y;
    const int b = blockIdx.z >> 2, ocg = blockIdx.z & 3;
    const int x0 = bx * 48;
    const int tid = threadIdx.x;
    const int wv = tid >> 6, lane = tid & 63;
    const int l15 = lane & 15, k8 = (lane >> 4) << 3;

    __shared__ __align__(16) ushort_t s_in[3 * 50 * 40];

    f32x4 acc[3];
#pragma unroll
    for (int i = 0; i < 3; ++i) acc[i] = (f32x4){0.f, 0.f, 0.f, 0.f};

    for (int chunk = 0; chunk < 2; ++chunk) {
        const int ci0 = chunk << 5;
        for (int i = tid; i < 600; i += 256) {
            int cvec = i & 3, rc = i >> 2;
            int row = rc / 50, col = rc - row * 50;
            int gy = y + row - 1, gx = x0 + col - 1;
            int4 v = {0, 0, 0, 0};
            if ((unsigned)gy < (unsigned)H_ && (unsigned)gx < (unsigned)W_)
                v = *(const int4*)&hbuf[(((size_t)b * H_ + gy) * W_ + gx) * 64 + ci0 + cvec * 8];
            *(int4*)&s_in[(row * 50 + col) * 40 + cvec * 8] = v;
        }
        bf16x8 af[9];
#pragma unroll
        for (int tap = 0; tap < 9; ++tap)
            af[tap] = *(const bf16x8*)&w2pf[(((((size_t)ocg * 2 + chunk) * 9 + tap) * 4 + wv) * 64 + lane) * 8];
        __syncthreads();

#pragma unroll
        for (int tap = 0; tap < 9; ++tap) {
            const int ky = tap / 3, kx = tap - ky * 3;
#pragma unroll
            for (int pt = 0; pt < 3; ++pt) {
                int col = (pt << 4) + l15 + kx;
                bf16x8 bb = *(const bf16x8*)&s_in[(ky * 50 + col) * 40 + k8];
                acc[pt] = __builtin_amdgcn_mfma_f32_16x16x32_bf16(af[tap], bb, acc[pt], 0, 0, 0);
            }
        }
        __syncthreads();
    }

    const int ocb = (wv << 4) + ((lane >> 4) << 2);
#pragma unroll
    for (int pt = 0; pt < 3; ++pt) {
        int gx = x0 + (pt << 4) + l15;
#pragma unroll
        for (int r = 0; r < 4; ++r) {
            int co = (ocg << 6) + ocb + r;
            if (co < 216) {
                float v = acc[pt][r] + b2[co];
                if (co < 144) {
                    off_out[((size_t)b * OFF_CH + co) * HW_ + y * W_ + gx] = v;
                } else {
                    maskbuf[((size_t)b * MASK_CH + (co - 144)) * HW_ + y * W_ + gx] =
                        f2bf(1.f / (1.f + expf(-v)));
                }
            }
        }
    }
}

// ---------------------------------------------------------------------------
// dconv v8 (round-11 proven, best total): barrier-free 2-deep ping-pong,
// full K (18 slices), per-dg-plane gathers, f32+bias direct store.
// grid 960, __launch_bounds__(256,4) = 128 VGPR/wave budget (do NOT raise:
// (256,8) caps at 64 VGPR and spills the pipeline — round 15).
// Split-K x2 + combine (rounds 12-16) nets ~+2us vs this — reverted.
// ---------------------------------------------------------------------------
struct OffRec { float dy, dx, m; };
struct Stage  { int4 g0, g1, g2, g3; float w0, w1, w2, w3; };

__global__ __launch_bounds__(256, 4) void dconv_mfma(
    const ushort_t* __restrict__ pin,
    const float* __restrict__ offs,
    const ushort_t* __restrict__ maskbuf,
    const ushort_t* __restrict__ wdp, const float* __restrict__ bd,
    float* __restrict__ outp)
{
    const int bid = blockIdx.x;
    const int nid = (bid & 7) * 120 + (bid >> 3);
    const int b   = nid / 480;
    const int rr_ = nid - b * 480;
    const int byt = rr_ / 15, bxt = rr_ - byt * 15;   // byt 0..31
    const int x0 = bxt << 4, y0 = byt << 2;

    const int tid = threadIdx.x;
    const int wv = tid >> 6, lane = tid & 63;
    const int l15 = lane & 15, hi4 = lane >> 4;       // hi4 = k-group

    const int x = x0 + l15, y = y0 + wv;              // this lane's pixel
    const size_t pix = (size_t)y * W_ + x;
    const size_t pinb = (size_t)b * 2 * HW_ * 64;     // nbr dg-planes base
    const float* offp = offs + (size_t)b * OFF_CH * HW_ + pix;
    const ushort_t* mkp = maskbuf + (size_t)b * MASK_CH * HW_ + pix;

    f32x4 acc0 = {0.f,0.f,0.f,0.f}, acc1 = {0.f,0.f,0.f,0.f};
    f32x4 acc2 = {0.f,0.f,0.f,0.f}, acc3 = {0.f,0.f,0.f,0.f};

    auto load_off = [&](int s) -> OffRec {
        int K = (s << 5) + (hi4 << 3);
        int dg = K / 72, r2 = K - dg * 72, tap = r2 >> 3;
        OffRec o;
        o.dy = offp[(size_t)(dg * 18 + tap) * HW_];
        o.dx = offp[(size_t)(dg * 18 + 9 + tap) * HW_];
        o.m  = bf2f(mkp[(size_t)(dg * 9 + tap) * HW_]);
        return o;
    };
    auto sample = [&](int s, OffRec of) -> Stage {
        int K = (s << 5) + (hi4 << 3);
        int dg = K / 72, rm = K - dg * 72, tap = rm >> 3;
        int ky = tap / 3 - 1, kx = tap % 3 - 1;
        float py  = (float)(y + ky) + of.dy;
        float pxf = (float)(x + kx) + of.dx;
        float yf = floorf(py), xf = floorf(pxf);
        float wy = py - yf, wx = pxf - xf;
        int yi = (int)yf, xi = (int)xf;
        bool y0v = (unsigned)yi < (unsigned)H_;
        bool y1v = (unsigned)(yi + 1) < (unsigned)H_;
        bool x0v = (unsigned)xi < (unsigned)W_;
        bool x1v = (unsigned)(xi + 1) < (unsigned)W_;
        Stage st;
        st.w0 = (y0v && x0v) ? (1.f - wy) * (1.f - wx) * of.m : 0.f;
        st.w1 = (y0v && x1v) ? (1.f - wy) * wx         * of.m : 0.f;
        st.w2 = (y1v && x0v) ? wy         * (1.f - wx) * of.m : 0.f;
        st.w3 = (y1v && x1v) ? wy         * wx         * of.m : 0.f;
        int yc0 = min(max(yi, 0), H_ - 1), yc1 = min(max(yi + 1, 0), H_ - 1);
        int xc0 = min(max(xi, 0), W_ - 1), xc1 = min(max(xi + 1, 0), W_ - 1);
        const size_t dgb = pinb + (size_t)dg * HW_ * 8;   // 16B px records
        st.g0 = *(const int4*)&pin[dgb + (size_t)(yc0 * W_ + xc0) * 8];
        st.g1 = *(const int4*)&pin[dgb + (size_t)(yc0 * W_ + xc1) * 8];
        st.g2 = *(const int4*)&pin[dgb + (size_t)(yc1 * W_ + xc0) * 8];
        st.g3 = *(const int4*)&pin[dgb + (size_t)(yc1 * W_ + xc1) * 8];
        return st;
    };

    // ---- prologue: stages for slices 0,1 in flight; offsets for 2,3 ----
    Stage  P0 = sample(0, load_off(0));
    Stage  P1 = sample(1, load_off(1));
    OffRec O0 = load_off(2);
    OffRec O1 = load_off(3);

#pragma unroll 2
    for (int s = 0; s < 18; ++s) {
        // A-fragments for slice s (L1/L2-resident)
        const ushort_t* wp = wdp + (((size_t)(s << 2) * 64) + lane) * 8;
        bf16x8 a0 = *(const bf16x8*)(wp);
        bf16x8 a1 = *(const bf16x8*)(wp + 512);
        bf16x8 a2 = *(const bf16x8*)(wp + 1024);
        bf16x8 a3 = *(const bf16x8*)(wp + 1536);

        // consume stage (s&1): blend -> bfrag  (s&1 is static after unroll)
        Stage cur = (s & 1) ? P1 : P0;
        bf16x8 bfrag;
        {
            const int* c00 = (const int*)&cur.g0; const int* c01 = (const int*)&cur.g1;
            const int* c10 = (const int*)&cur.g2; const int* c11 = (const int*)&cur.g3;
#pragma unroll
            for (int j = 0; j < 4; ++j) {
                float lo = cur.w0 * bf_lo(c00[j]) + cur.w1 * bf_lo(c01[j])
                         + cur.w2 * bf_lo(c10[j]) + cur.w3 * bf_lo(c11[j]);
                float hv = cur.w0 * bf_hi(c00[j]) + cur.w1 * bf_hi(c01[j])
                         + cur.w2 * bf_hi(c10[j]) + cur.w3 * bf_hi(c11[j]);
                bfrag[2 * j]     = (__bf16)lo;
                bfrag[2 * j + 1] = (__bf16)hv;
            }
        }

        // re-fill consumed stage with slice s+2 (clamped tail)
        int s2 = min(s + 2, 17);
        if (s & 1) P1 = sample(s2, O1); else P0 = sample(s2, O0);
        int s4 = min(s + 4, 17);
        if (s & 1) O1 = load_off(s4); else O0 = load_off(s4);

        acc0 = __builtin_amdgcn_mfma_f32_16x16x32_bf16(a0, bfrag, acc0, 0, 0, 0);
        acc1 = __builtin_amdgcn_mfma_f32_16x16x32_bf16(a1, bfrag, acc1, 0, 0, 0);
        acc2 = __builtin_amdgcn_mfma_f32_16x16x32_bf16(a2, bfrag, acc2, 0, 0, 0);
        acc3 = __builtin_amdgcn_mfma_f32_16x16x32_bf16(a3, bfrag, acc3, 0, 0, 0);
    }

    // epilogue: acc_g[r] -> oc = g*16 + hi4*4 + r at pixel (y, x0+l15)
    const int ocr = hi4 << 2;
    const size_t pbase = (size_t)b * C_ * HW_ + (size_t)y * W_ + x0 + l15;
#pragma unroll
    for (int r = 0; r < 4; ++r) {
        int oc0 = ocr + r;
        outp[pbase + (size_t)(oc0)      * HW_] = acc0[r] + bd[oc0];
        outp[pbase + (size_t)(oc0 + 16) * HW_] = acc1[r] + bd[oc0 + 16];
        outp[pbase + (size_t)(oc0 + 32) * HW_] = acc2[r] + bd[oc0 + 32];
        outp[pbase + (size_t)(oc0 + 48) * HW_] = acc3[r] + bd[oc0 + 48];
    }
}

// ---------------------------------------------------------------------------
extern "C" void kernel_launch(void* const* d_in, const int* in_sizes, int n_in,
                              void* d_out, int out_size, void* d_ws, size_t ws_size,
                              hipStream_t stream)
{
    const float* nbr = (const float*)d_in[0];
    const float* ref = (const float*)d_in[1];
    const float* w1  = (const float*)d_in[2];
    const float* b1  = (const float*)d_in[3];
    const float* w2  = (const float*)d_in[4];
    const float* b2  = (const float*)d_in[5];
    const float* wd  = (const float*)d_in[6];
    const float* bd  = (const float*)d_in[7];

    float* out     = (float*)d_out;
    float* off_out = out + ALIGNED_SZ;

    char* ws = (char*)d_ws;
    ushort_t* w1pf  = (ushort_t*)(ws + W1P_OFF);
    ushort_t* w2pf  = (ushort_t*)(ws + W2P_OFF);
    ushort_t* pin   = (ushort_t*)(ws + PIN_OFF);
    ushort_t* hbufp = (ushort_t*)(ws + HBUF_OFF);
    ushort_t* maskp = (ushort_t*)(ws + MASK_OFF);
    ushort_t* wdp   = (ushort_t*)(ws + WDP_OFF);

    dim3 blk(256, 1, 1);
    pack_weights<<<1008, blk, 0, stream>>>(w1, w2, wd, w1pf, w2pf, wdp);
    pack_input<<<3840, blk, 0, stream>>>(nbr, ref, pin);
    conv1_mfma<<<dim3(5, 128, 2), blk, 0, stream>>>(pin, b1, w1pf, hbufp);
    conv2_mfma<<<dim3(5, 128, 8), blk, 0, stream>>>(hbufp, b2, w2pf, off_out, maskp);
    dconv_mfma<<<960, blk, 0, stream>>>(pin, off_out, maskp, wdp, bd, out);
}